// Round 7
// baseline (3606.477 us; speedup 1.0000x reference)
//
#include <hip/hip_runtime.h>
#include <hip/hip_fp16.h>
#include <math.h>

#define NN    100000
#define FEATS 512
#define HID   64
#define EE    3200000
#define NBUCK 3       // source-range buckets (slice ~33.3K nodes * 128B = 4.27MB ~ per-XCD L2)
#define BUCKW 32      // ELL width per bucket; in-deg/bucket ~ Pois(10.67), P(>=33) ~ 6e-25
#define ROWW  (NBUCK * BUCKW)   // 96 ints per node
#define SLICE 33334   // ceil(NN / NBUCK)
#define CONV_NB  768  // persistent conv grid: 3 blocks/CU
#define WPB   4       // waves per block
#define NPW   33      // nodes per wave: 768*4*33 = 101376 >= NN

// ================================================================ ELL build (bucketed)
// One pass: deg_out histogram + bucketed ELL scatter by dst.
// fill3[d*3+b] counts edges into d from source-bucket b (unclamped = true count).
__global__ void ell_build(const int* __restrict__ src, const int* __restrict__ dst,
                          int* __restrict__ deg_out, int* __restrict__ fill3,
                          int* __restrict__ col) {
  int stride = gridDim.x * blockDim.x;
  int tid = blockIdx.x * blockDim.x + threadIdx.x;
  const int4* s4 = reinterpret_cast<const int4*>(src);
  const int4* d4 = reinterpret_cast<const int4*>(dst);
  for (int q = tid; q < EE / 4; q += stride) {
    int4 s = s4[q];
    int4 d = d4[q];
    atomicAdd(&deg_out[s.x], 1);
    atomicAdd(&deg_out[s.y], 1);
    atomicAdd(&deg_out[s.z], 1);
    atomicAdd(&deg_out[s.w], 1);
    int b0 = s.x / SLICE, b1 = s.y / SLICE, b2 = s.z / SLICE, b3 = s.w / SLICE;
    int p0 = atomicAdd(&fill3[d.x * NBUCK + b0], 1);
    if (p0 < BUCKW) col[(size_t)d.x * ROWW + b0 * BUCKW + p0] = s.x;
    int p1 = atomicAdd(&fill3[d.y * NBUCK + b1], 1);
    if (p1 < BUCKW) col[(size_t)d.y * ROWW + b1 * BUCKW + p1] = s.y;
    int p2 = atomicAdd(&fill3[d.z * NBUCK + b2], 1);
    if (p2 < BUCKW) col[(size_t)d.z * ROWW + b2 * BUCKW + p2] = s.z;
    int p3 = atomicAdd(&fill3[d.w * NBUCK + b3], 1);
    if (p3 < BUCKW) col[(size_t)d.w * ROWW + b3 * BUCKW + p3] = s.w;
  }
}

// ================================================================ node prep
__global__ void node_prep(const int* __restrict__ dout, const int* __restrict__ fill3,
                          float* __restrict__ r_out, float* __restrict__ rr,
                          float* __restrict__ inv_r_out) {
  int i = blockIdx.x * 256 + threadIdx.x;
  if (i >= NN) return;
  int a = dout[i]; if (a < 1) a = 1;
  int b = fill3[i * NBUCK] + fill3[i * NBUCK + 1] + fill3[i * NBUCK + 2];  // true in-deg
  if (b < 1) b = 1;
  float ro = rsqrtf((float)a);
  r_out[i] = ro;
  rr[i] = ro * rsqrtf((float)b);
  inv_r_out[i] = sqrtf((float)a);
}

// ================================================================ fused MLP:
// h = relu(x@w1+b1); logits = h@w2+b2; p = softmax(logits);
// err0_t = r_out .* ((train ? onehot : 0) - p)   (fp16, t-space)
__global__ __launch_bounds__(256) void fused_mlp(const float* __restrict__ x,
                                                 const float* __restrict__ w1,
                                                 const float* __restrict__ b1,
                                                 const float* __restrict__ w2,
                                                 const float* __restrict__ b2,
                                                 const int* __restrict__ mask,
                                                 const int* __restrict__ labels,
                                                 const float* __restrict__ r_out,
                                                 float* __restrict__ p,
                                                 __half* __restrict__ err0) {
  __shared__ float hs[64 * 65];    // 16.6 KB
  __shared__ float w2s[64 * 64];   // 16 KB; aliased as xs+ws during gemm1
  float* xs = w2s;                 // [64][17]
  float* ws = w2s + 64 * 17;       // [16][64]
  int t = threadIdx.x;
  int row0 = blockIdx.x * 64;
  int tx = t & 15, ty = t >> 4;
  int lr = t >> 2, lq = t & 3;
  int wk = t >> 4, wc = (t & 15) * 4;
  float acc[4][4] = {};
  for (int k0 = 0; k0 < FEATS; k0 += 16) {
    float4 xv = make_float4(0.f, 0.f, 0.f, 0.f);
    int gr = row0 + lr;
    if (gr < NN) xv = *reinterpret_cast<const float4*>(x + (size_t)gr * FEATS + k0 + lq * 4);
    float4 wv = *reinterpret_cast<const float4*>(w1 + (size_t)(k0 + wk) * HID + wc);
    xs[lr * 17 + lq * 4 + 0] = xv.x; xs[lr * 17 + lq * 4 + 1] = xv.y;
    xs[lr * 17 + lq * 4 + 2] = xv.z; xs[lr * 17 + lq * 4 + 3] = xv.w;
    ws[wk * 64 + wc + 0] = wv.x; ws[wk * 64 + wc + 1] = wv.y;
    ws[wk * 64 + wc + 2] = wv.z; ws[wk * 64 + wc + 3] = wv.w;
    __syncthreads();
#pragma unroll
    for (int kk = 0; kk < 16; ++kk) {
      float a[4], b[4];
#pragma unroll
      for (int ii = 0; ii < 4; ++ii) a[ii] = xs[(ty * 4 + ii) * 17 + kk];
#pragma unroll
      for (int jj = 0; jj < 4; ++jj) b[jj] = ws[kk * 64 + tx * 4 + jj];
#pragma unroll
      for (int ii = 0; ii < 4; ++ii)
#pragma unroll
        for (int jj = 0; jj < 4; ++jj) acc[ii][jj] = fmaf(a[ii], b[jj], acc[ii][jj]);
    }
    __syncthreads();
  }
  float bb[4];
#pragma unroll
  for (int jj = 0; jj < 4; ++jj) bb[jj] = b1[tx * 4 + jj];
#pragma unroll
  for (int ii = 0; ii < 4; ++ii)
#pragma unroll
    for (int jj = 0; jj < 4; ++jj)
      hs[(ty * 4 + ii) * 65 + tx * 4 + jj] = fmaxf(acc[ii][jj] + bb[jj], 0.f);
#pragma unroll
  for (int q = 0; q < 16; ++q) w2s[t + q * 256] = w2[t + q * 256];
  __syncthreads();
  float lg[4][4];
#pragma unroll
  for (int jj = 0; jj < 4; ++jj) {
    float b2v = b2[tx * 4 + jj];
#pragma unroll
    for (int ii = 0; ii < 4; ++ii) lg[ii][jj] = b2v;
  }
#pragma unroll 4
  for (int k = 0; k < 64; ++k) {
    float hk[4];
#pragma unroll
    for (int ii = 0; ii < 4; ++ii) hk[ii] = hs[(ty * 4 + ii) * 65 + k];
#pragma unroll
    for (int jj = 0; jj < 4; ++jj) {
      float wv2 = w2s[k * 64 + tx * 4 + jj];
#pragma unroll
      for (int ii = 0; ii < 4; ++ii) lg[ii][jj] = fmaf(hk[ii], wv2, lg[ii][jj]);
    }
  }
  __syncthreads();
#pragma unroll
  for (int ii = 0; ii < 4; ++ii)
#pragma unroll
    for (int jj = 0; jj < 4; ++jj)
      hs[(ty * 4 + ii) * 65 + tx * 4 + jj] = lg[ii][jj];
  __syncthreads();
  int wv_ = t >> 6, lane = t & 63;
  for (int q = 0; q < 16; ++q) {
    int r = wv_ * 16 + q;
    int i = row0 + r;
    if (i >= NN) break;
    float v = hs[r * 65 + lane];
    float m = v;
#pragma unroll
    for (int off = 32; off >= 1; off >>= 1) m = fmaxf(m, __shfl_xor(m, off));
    float e = expf(v - m);
    float s = e;
#pragma unroll
    for (int off = 32; off >= 1; off >>= 1) s += __shfl_xor(s, off);
    float pv = e / s;
    size_t off64 = (size_t)i * 64 + lane;
    p[off64] = pv;
    float oh = (mask[i] != 0 && labels[i] == lane) ? 1.f : 0.f;
    err0[off64] = __float2half(r_out[i] * (oh - pv));  // t-space
  }
}

// ================================================================ persistent phased conv
// Soft-lockstep: all CONV_NB blocks co-resident; every wave sweeps bucket p of
// all its NPW nodes before bucket p+1, so the whole cohort gathers from one
// 4.27MB source slice at a time -> L2-resident gathers. LDS accumulators
// (wave-private, no syncs). MODE 1: loop1 (train rows copy). MODE 2: loop2.
// MODE 3: loop2 final with fused log epilogue (fp32 out).
template <int MODE>
__global__ __launch_bounds__(256) void conv_p(const int* __restrict__ fill3,
                                              const int* __restrict__ col,
                                              const float* __restrict__ rr,
                                              const float* __restrict__ inv_r_out,
                                              const int* __restrict__ mask,
                                              const __half* __restrict__ in,
                                              const __half* __restrict__ uinit,
                                              __half* __restrict__ out,
                                              float* __restrict__ fout) {
  __shared__ float sacc[WPB * NPW * 64];   // 33.8 KB
  int t = threadIdx.x;
  int w = t >> 6, lane = t & 63;
  int gw = blockIdx.x * WPB + w;
  int n0 = gw * NPW;
  float* sbase = sacc + (w * NPW) * 64;
  for (int j = 0; j < NPW; ++j) sbase[j * 64 + lane] = 0.f;  // wave-private, no sync
  for (int p = 0; p < NBUCK; ++p) {
    for (int j = 0; j < NPW; ++j) {
      int node = n0 + j;
      if (node >= NN) break;
      if (MODE == 1 && mask[node] != 0) continue;  // train dst: copy at epilogue
      int cnt = fill3[node * NBUCK + p];
      if (cnt > BUCKW) cnt = BUCKW;
      if (cnt == 0) continue;
      const int* cp = col + (size_t)node * ROWW + p * BUCKW;  // 128B-aligned
      float rsum = 0.f;
      for (int e = 0; e < cnt; e += 16) {  // clamped 16-deep batch, no scalar tail
        int cc[16];
#pragma unroll
        for (int q = 0; q < 4; ++q) {
          int4 c4 = *reinterpret_cast<const int4*>(cp + e + q * 4);
          cc[q * 4 + 0] = c4.x; cc[q * 4 + 1] = c4.y;
          cc[q * 4 + 2] = c4.z; cc[q * 4 + 3] = c4.w;
        }
        int rem = cnt - e;
        int c0 = cc[0];
#pragma unroll
        for (int jj = 0; jj < 16; ++jj)
          if (jj >= rem) cc[jj] = c0;
        float vv[16];
#pragma unroll
        for (int jj = 0; jj < 16; ++jj) vv[jj] = __half2float(in[(size_t)cc[jj] * 64 + lane]);
#pragma unroll
        for (int jj = 0; jj < 16; ++jj) rsum += (jj < rem) ? vv[jj] : 0.f;
      }
      sbase[j * 64 + lane] += rsum;
    }
  }
  // epilogue
  for (int j = 0; j < NPW; ++j) {
    int node = n0 + j;
    if (node >= NN) break;
    size_t off = (size_t)node * 64 + lane;
    float sum = sbase[j * 64 + lane];
    if (MODE == 1) {
      out[off] = (mask[node] != 0) ? in[off] : __float2half(rr[node] * sum);
    } else {
      float f = fmaf(0.9f * rr[node], sum, 0.1f * __half2float(uinit[off]));
      if (MODE == 2) out[off] = __float2half(f);
      else           fout[off] = logf(f * inv_r_out[node] + 1.f);
    }
  }
}

// ================================================================ combine:
// u_init = r_out .* p + t10   (fp16, half2-vectorized)
__global__ void combine_kernel(const float* __restrict__ p, const __half* __restrict__ t10,
                               const float* __restrict__ r_out, __half* __restrict__ u) {
  int idx = blockIdx.x * 256 + threadIdx.x;
  if (idx >= NN * 32) return;
  int i = idx >> 5;
  float ro = r_out[i];
  float2 pv = reinterpret_cast<const float2*>(p)[idx];
  __half2 tv = reinterpret_cast<const __half2*>(t10)[idx];
  float2 tf = __half22float2(tv);
  reinterpret_cast<__half2*>(u)[idx] =
      __floats2half2_rn(fmaf(ro, pv.x, tf.x), fmaf(ro, pv.y, tf.y));
}

// ================================================================ launch
extern "C" void kernel_launch(void* const* d_in, const int* in_sizes, int n_in,
                              void* d_out, int out_size, void* d_ws, size_t ws_size,
                              hipStream_t stream) {
  const float* x      = (const float*)d_in[0];
  const float* w1     = (const float*)d_in[1];
  const float* b1     = (const float*)d_in[2];
  const float* w2     = (const float*)d_in[3];
  const float* b2     = (const float*)d_in[4];
  const int*   edges  = (const int*)d_in[5];
  const int*   mask   = (const int*)d_in[6];
  const int*   labels = (const int*)d_in[7];
  const int*   src = edges;
  const int*   dst = edges + EE;

  char* w = (char*)d_ws;
  auto alloc = [&](size_t bytes) -> char* {
    char* pp = w;
    w += (bytes + 255) & ~(size_t)255;
    return pp;
  };
  int*    deg_out = (int*)alloc((size_t)NN * 4);
  int*    fill3   = (int*)alloc((size_t)NN * NBUCK * 4);
  float*  r_out   = (float*)alloc((size_t)NN * 4);
  float*  rr      = (float*)alloc((size_t)NN * 4);
  float*  inv_ro  = (float*)alloc((size_t)NN * 4);
  float*  P       = (float*)alloc((size_t)NN * HID * 4);        // softmax p (fp32)
  __half* E       = (__half*)alloc((size_t)NN * HID * 2);       // err0 / ping
  __half* F       = (__half*)alloc((size_t)NN * HID * 2);       // pong
  __half* U       = (__half*)alloc((size_t)NN * HID * 2);       // u_init anchor
  int*    col     = (int*)alloc((size_t)NN * ROWW * 4 + 256);   // bucketed ELL + overrun pad
  // total ~105 MB (within proven ws budget)

  // zero deg_out + fill3 (contiguous)
  hipMemsetAsync(deg_out, 0, (size_t)((char*)r_out - (char*)deg_out), stream);

  const int SCAN_NB = (NN + 255) / 256;

  ell_build<<<2048, 256, 0, stream>>>(src, dst, deg_out, fill3, col);
  node_prep<<<SCAN_NB, 256, 0, stream>>>(deg_out, fill3, r_out, rr, inv_ro);
  fused_mlp<<<(NN + 63) / 64, 256, 0, stream>>>(x, w1, b1, w2, b2, mask, labels,
                                                r_out, P, E);

#define CONV(MODE, IN, UI, OUT, FOUT)                                        \
  conv_p<MODE><<<CONV_NB, 256, 0, stream>>>(fill3, col, rr, inv_ro, mask,    \
                                            IN, UI, OUT, FOUT)

  // loop 1 (err propagation, t-space): 10 pure-sum hops; t10 ends in E.
  {
    __half* in = E; __half* out = F;
    for (int it = 0; it < 10; ++it) {
      CONV(1, in, (__half*)nullptr, out, (float*)nullptr);
      __half* tmp = in; in = out; out = tmp;
    }
  }

  // u_init = r_out.*p + t10
  combine_kernel<<<(NN * 32 + 255) / 256, 256, 0, stream>>>(P, E, r_out, U);

  // loop 2 (smoothing, u-space): 9 x MODE2 + final MODE3 fused log epilogue.
  CONV(2, U, U, F, (float*)nullptr);  // c1: U -> F
  {
    __half* in = F; __half* out = E;
    for (int it = 1; it < 9; ++it) {
      CONV(2, in, U, out, (float*)nullptr);
      __half* tmp = in; in = out; out = tmp;
    }
    // after c9, current value in F
  }
  CONV(3, F, U, (__half*)nullptr, (float*)d_out);
#undef CONV
}